// Round 7
// baseline (553.651 us; speedup 1.0000x reference)
//
#include <hip/hip_runtime.h>
#include <hip/hip_bf16.h>

#define H 768
#define NH 12
#define DH 64
#define NNODES 2048
#define NEDGES 131072

typedef __bf16 bf16x8 __attribute__((ext_vector_type(8)));
typedef float floatx4 __attribute__((ext_vector_type(4)));

// direct global->LDS DMA, 16B per lane (dest must be wave-uniform base + lane*16)
#define GLOAD_LDS16(gptr, ldsptr)                                                        \
  __builtin_amdgcn_global_load_lds((const __attribute__((address_space(1))) void*)(gptr), \
                                   (__attribute__((address_space(3))) void*)(ldsptr),     \
                                   16, 0, 0)

__device__ __forceinline__ unsigned short f2bf(float x) {
  union { __hip_bfloat16 h; unsigned short u; } cv;
  cv.h = __float2bfloat16(x);
  return cv.u;
}

// exact bf16 -> fp32 (bit shift)
__device__ __forceinline__ float bfu2f(unsigned short u) {
  union { float f; unsigned int i; } c;
  c.i = ((unsigned int)u) << 16;
  return c.f;
}

// ---------------- fp32 -> bf16 conversion (vectorized x4) + hist zero -------
__global__ __launch_bounds__(256)
void convert_kernel(const float* __restrict__ hs,
                    const float* __restrict__ Wq,
                    const float* __restrict__ Wk,
                    const float* __restrict__ Wv,
                    __hip_bfloat16* __restrict__ hsb,
                    __hip_bfloat16* __restrict__ wb,
                    int* __restrict__ hists) {   // hist1 ++ hist2, 4096 ints
  int i = blockIdx.x * 256 + threadIdx.x;
  const int n_hs4 = NNODES * H / 4;   // 393216
  const int n_w4  = H * H / 4;        // 147456
  if (i < n_hs4) {
    float4 v = ((const float4*)hs)[i];
    ((ushort4*)hsb)[i] = make_ushort4(f2bf(v.x), f2bf(v.y), f2bf(v.z), f2bf(v.w));
    return;
  }
  int j = i - n_hs4;
  if (j < 3 * n_w4) {
    const float* src = (j < n_w4) ? Wq : (j < 2 * n_w4 ? Wk : Wv);
    float4 v = ((const float4*)src)[j % n_w4];
    ((ushort4*)wb)[j] = make_ushort4(f2bf(v.x), f2bf(v.y), f2bf(v.z), f2bf(v.w));
    return;
  }
  int z = j - 3 * n_w4;
  if (z < 2 * NNODES / 4) {           // 1024 int4 = 4096 ints (both hists)
    ((int4*)hists)[z] = make_int4(0, 0, 0, 0);
  }
}

// ---------------- QKV projection GEMM: C = A * W^T + bias -------------------
// 64x64 tiles, grid (32,12,3) = 1152 blocks; K (mat==1) emitted as bf16.
__global__ __launch_bounds__(256)
void qkv_gemm(const __hip_bfloat16* __restrict__ A,
              const __hip_bfloat16* __restrict__ Wb,
              const float* __restrict__ b0,
              const float* __restrict__ b1,
              const float* __restrict__ b2,
              float* __restrict__ out,
              __hip_bfloat16* __restrict__ kb) {
  __shared__ __hip_bfloat16 As[64][32];
  __shared__ __hip_bfloat16 Bs[64][32];

  const int t    = threadIdx.x;
  const int wave = t >> 6;
  const int lane = t & 63;
  const int bm   = blockIdx.x * 64;
  const int bn   = blockIdx.y * 64;
  const int mat  = blockIdx.z;

  const __hip_bfloat16* B = Wb + (size_t)mat * H * H;
  const float* bias = (mat == 0) ? b0 : ((mat == 1) ? b1 : b2);

  const int wm = (wave & 1) * 32;
  const int wn = (wave >> 1) * 32;
  const int lr = lane & 15;
  const int lq = lane >> 4;

  floatx4 acc[2][2] = {};

  const int ar = t >> 2;
  const int ac = (t & 3) * 8;
  __hip_bfloat16* AsF = &As[0][0];
  __hip_bfloat16* BsF = &Bs[0][0];

  for (int kt = 0; kt < H; kt += 32) {
    GLOAD_LDS16(A + (size_t)(bm + ar) * H + kt + ac, AsF + t * 8);
    GLOAD_LDS16(B + (size_t)(bn + ar) * H + kt + ac, BsF + t * 8);
    __syncthreads();

    bf16x8 af[2], bfr[2];
#pragma unroll
    for (int i = 0; i < 2; i++)
      af[i] = *(const bf16x8*)&As[wm + i * 16 + lr][lq * 8];
#pragma unroll
    for (int i = 0; i < 2; i++)
      bfr[i] = *(const bf16x8*)&Bs[wn + i * 16 + lr][lq * 8];
#pragma unroll
    for (int mi = 0; mi < 2; mi++)
#pragma unroll
      for (int ni = 0; ni < 2; ni++)
        acc[mi][ni] = __builtin_amdgcn_mfma_f32_16x16x32_bf16(
            af[mi], bfr[ni], acc[mi][ni], 0, 0, 0);
    __syncthreads();
  }

  // epilogue: C/D layout col = lane&15, row = (lane>>4)*4 + reg  [m89-verified]
  if (mat == 1) {
#pragma unroll
    for (int ni = 0; ni < 2; ni++) {
      int col = bn + wn + ni * 16 + lr;
      float bv = bias[col];
#pragma unroll
      for (int mi = 0; mi < 2; mi++) {
#pragma unroll
        for (int r = 0; r < 4; r++) {
          int row = bm + wm + mi * 16 + lq * 4 + r;
          kb[(size_t)row * H + col] = __float2bfloat16(acc[mi][ni][r] + bv);
        }
      }
    }
  } else {
    float* C = out + (size_t)mat * NNODES * H;
#pragma unroll
    for (int ni = 0; ni < 2; ni++) {
      int col = bn + wn + ni * 16 + lr;
      float bv = bias[col];
#pragma unroll
      for (int mi = 0; mi < 2; mi++) {
#pragma unroll
        for (int r = 0; r < 4; r++) {
          int row = bm + wm + mi * 16 + lq * 4 + r;
          C[(size_t)row * H + col] = acc[mi][ni][r] + bv;
        }
      }
    }
  }
}

// ---------------- dual histogram (tgt + src) --------------------------------
__global__ __launch_bounds__(256)
void hist_kernel(const int* __restrict__ etgt, const int* __restrict__ esrc,
                 int* __restrict__ hist1, int* __restrict__ hist2) {
  int e = blockIdx.x * 256 + threadIdx.x;
  atomicAdd(&hist1[etgt[e]], 1);
  atomicAdd(&hist2[esrc[e]], 1);
}

// ---------------- dual exclusive prefix sum (1 block) -----------------------
__global__ __launch_bounds__(256)
void scan_kernel(const int* __restrict__ hist1, int* __restrict__ rowptr1,
                 int* __restrict__ cursor1,
                 const int* __restrict__ hist2, int* __restrict__ rowptr2,
                 int* __restrict__ cursor2) {
  __shared__ int part[256];
  int t = threadIdx.x;

  // ---- scan 1 (tgt) ----
  {
    int loc[8]; int s = 0;
#pragma unroll
    for (int k = 0; k < 8; k++) { loc[k] = s; s += hist1[t * 8 + k]; }
    part[t] = s;
    __syncthreads();
    for (int off = 1; off < 256; off <<= 1) {
      int v = (t >= off) ? part[t - off] : 0;
      __syncthreads();
      if (t >= off) part[t] += v;
      __syncthreads();
    }
    int pre = part[t] - s;
#pragma unroll
    for (int k = 0; k < 8; k++) {
      rowptr1[t * 8 + k] = pre + loc[k];
      cursor1[t * 8 + k] = pre + loc[k];
    }
    if (t == 255) rowptr1[NNODES] = part[255];
  }
  __syncthreads();
  // ---- scan 2 (src) ----
  {
    int loc[8]; int s = 0;
#pragma unroll
    for (int k = 0; k < 8; k++) { loc[k] = s; s += hist2[t * 8 + k]; }
    part[t] = s;
    __syncthreads();
    for (int off = 1; off < 256; off <<= 1) {
      int v = (t >= off) ? part[t - off] : 0;
      __syncthreads();
      if (t >= off) part[t] += v;
      __syncthreads();
    }
    int pre = part[t] - s;
#pragma unroll
    for (int k = 0; k < 8; k++) {
      rowptr2[t * 8 + k] = pre + loc[k];
      cursor2[t * 8 + k] = pre + loc[k];
    }
    if (t == 255) rowptr2[NNODES] = part[255];
  }
}

// ---------------- dual scatter: tgt-CSR (for scores) + src-CSR (for out) ----
__global__ __launch_bounds__(256)
void scatter_kernel(const int* __restrict__ esrc, const int* __restrict__ etgt,
                    const int* __restrict__ epos,
                    int* __restrict__ cursor1, int* __restrict__ cursor2,
                    int* __restrict__ src_s, int* __restrict__ pos_s,
                    int* __restrict__ tslot2, int* __restrict__ pos2,
                    int* __restrict__ eorig2) {
  int e = blockIdx.x * 256 + threadIdx.x;
  int tgt = etgt[e], src = esrc[e], pos = epos[e];
  int s1 = atomicAdd(&cursor1[tgt], 1);
  src_s[s1] = src;
  pos_s[s1] = pos;
  int s2 = atomicAdd(&cursor2[src], 1);
  tslot2[s2] = s1;     // cross-link: where this edge's attn lives (tgt order)
  pos2[s2]   = pos;
  eorig2[s2] = e;      // original edge id -> output location
}

// ---------------- pass1: per-tgt block; scores + in-place normalize ---------
// Output: attn[slot*NH+h] = exp(qk/8)/denom, in tgt-sorted slot order.
__global__ __launch_bounds__(256)
void edge_scores_kernel(const float* __restrict__ Q,
                        const __hip_bfloat16* __restrict__ Kb,
                        const float* __restrict__ relk,
                        const int* __restrict__ rowptr1,
                        const int* __restrict__ src_s,
                        const int* __restrict__ pos_s,
                        float* __restrict__ attn) {
  const int t    = blockIdx.x;
  const int tid  = threadIdx.x;
  const int wave = tid >> 6;
  const int lane = tid & 63;
  const int g    = lane >> 4;
  const int off  = (lane & 15) * 4;

  __shared__ float Qs[H];            // 3 KB
  __shared__ float Rk[16 * DH];      // 4 KB
  __shared__ float dpart[4][NH];
  __shared__ float dinv[NH];

  if (tid < 192)
    *(float4*)&Qs[tid * 4] = *(const float4*)(Q + (size_t)t * H + tid * 4);
  *(float4*)&Rk[tid * 4] = *(const float4*)(relk + tid * 4);
  __syncthreads();

  const int beg = rowptr1[t], end = rowptr1[t + 1];
  float dacc0 = 0.f, dacc1 = 0.f, dacc2 = 0.f;

  for (int i = beg + wave; i < end; i += 4) {
    const int src = src_s[i];
    const int pos = pos_s[i];
    const unsigned short* Kp = (const unsigned short*)(Kb + (size_t)src * H);
    const float4 r4 = *(const float4*)&Rk[pos * DH + off];
    float s[3];
#pragma unroll
    for (int c = 0; c < 3; c++) {
      ushort4 ku = *(const ushort4*)(Kp + c * 256 + lane * 4);
      float4 q4 = *(const float4*)&Qs[c * 256 + lane * 4];
      s[c] = q4.x * (bfu2f(ku.x) + r4.x) + q4.y * (bfu2f(ku.y) + r4.y) +
             q4.z * (bfu2f(ku.z) + r4.z) + q4.w * (bfu2f(ku.w) + r4.w);
    }
#pragma unroll
    for (int m = 1; m < 16; m <<= 1) {
      s[0] += __shfl_xor(s[0], m);
      s[1] += __shfl_xor(s[1], m);
      s[2] += __shfl_xor(s[2], m);
    }
    if ((lane & 15) == 0) {
      float sc0 = __expf(s[0] * 0.125f);
      float sc1 = __expf(s[1] * 0.125f);
      float sc2 = __expf(s[2] * 0.125f);
      attn[(size_t)i * NH + g]     = sc0;
      attn[(size_t)i * NH + 4 + g] = sc1;
      attn[(size_t)i * NH + 8 + g] = sc2;
      dacc0 += sc0; dacc1 += sc1; dacc2 += sc2;
    }
  }

  if ((lane & 15) == 0) {
    dpart[wave][g]     = dacc0;
    dpart[wave][4 + g] = dacc1;
    dpart[wave][8 + g] = dacc2;
  }
  __syncthreads();   // drains pass-score stores (vmcnt(0) before s_barrier)

  if (tid < NH) {
    float den = dpart[0][tid] + dpart[1][tid] + dpart[2][tid] + dpart[3][tid];
    dinv[tid] = 1.0f / den;
  }
  __syncthreads();

  // in-place normalize: attn[m] *= dinv[m%12], vectorized float4 (12 = 3 f4)
  float4* aF4 = (float4*)attn;
  const int b3 = beg * 3, e3 = end * 3;
  for (int k4 = b3 + tid; k4 < e3; k4 += 256) {
    int c = k4 % 3;                       // chunk within the 12-head row
    float4 v = aF4[k4];
    float4 d = *(const float4*)&dinv[c * 4];
    v.x *= d.x; v.y *= d.y; v.z *= d.z; v.w *= d.w;
    aF4[k4] = v;
  }
}

// ---------------- pass2: per-src block; V staged once, stream out -----------
__global__ __launch_bounds__(256)
void edge_out_kernel(const float* __restrict__ V,
                     const float* __restrict__ relv,
                     const int* __restrict__ rowptr2,
                     const int* __restrict__ tslot2,
                     const int* __restrict__ pos2,
                     const int* __restrict__ eorig2,
                     const float* __restrict__ attn,
                     float* __restrict__ out) {
  const int s    = blockIdx.x;
  const int tid  = threadIdx.x;
  const int wave = tid >> 6;
  const int lane = tid & 63;
  const int g    = lane >> 4;
  const int off  = (lane & 15) * 4;

  __shared__ float Vs[H];            // 3 KB (this src's V row, read ONCE)
  __shared__ float Rv[16 * DH];      // 4 KB

  if (tid < 192)
    *(float4*)&Vs[tid * 4] = *(const float4*)(V + (size_t)s * H + tid * 4);
  *(float4*)&Rv[tid * 4] = *(const float4*)(relv + tid * 4);
  __syncthreads();

  const int beg = rowptr2[s], end = rowptr2[s + 1];
  for (int j = beg + wave; j < end; j += 4) {
    const int tslot = tslot2[j];
    const int pos   = pos2[j];
    const int e     = eorig2[j];
    const float4 r4 = *(const float4*)&Rv[pos * DH + off];
#pragma unroll
    for (int c = 0; c < 3; c++) {
      float a = attn[(size_t)tslot * NH + c * 4 + g];
      float4 v4 = *(const float4*)&Vs[c * 256 + lane * 4];
      floatx4 o;
      o.x = (v4.x + r4.x) * a;
      o.y = (v4.y + r4.y) * a;
      o.z = (v4.z + r4.z) * a;
      o.w = (v4.w + r4.w) * a;
      __builtin_nontemporal_store(
          o, (floatx4*)(out + (size_t)e * H + c * 256 + lane * 4));
    }
  }
}

extern "C" void kernel_launch(void* const* d_in, const int* in_sizes, int n_in,
                              void* d_out, int out_size, void* d_ws, size_t ws_size,
                              hipStream_t stream) {
  const float* hs   = (const float*)d_in[0];
  const float* Wq   = (const float*)d_in[1];
  const float* bq   = (const float*)d_in[2];
  const float* Wk   = (const float*)d_in[3];
  const float* bk   = (const float*)d_in[4];
  const float* Wv   = (const float*)d_in[5];
  const float* bv   = (const float*)d_in[6];
  const float* relk = (const float*)d_in[7];
  const float* relv = (const float*)d_in[8];
  const int* esrc   = (const int*)d_in[9];
  const int* etgt   = (const int*)d_in[10];
  const int* epos   = (const int*)d_in[12];
  float* out = (float*)d_out;

  char* ws = (char*)d_ws;
  __hip_bfloat16* hsb = (__hip_bfloat16*)ws;                 //  3,145,728 B
  __hip_bfloat16* wb  = (__hip_bfloat16*)(ws + 3145728);     //  3,538,944 B
  float* qkv   = (float*)(ws + 6684672);                     // 18,874,368 B (K slot unused)
  float* attn  = (float*)(ws + 25559040);                    //  6,291,456 B
  int* hist1   = (int*)(ws + 31850496);                      //      8,192 B
  int* hist2   = (int*)(ws + 31858688);                      //      8,192 B (contig w/ hist1)
  int* rowptr1 = (int*)(ws + 31866880);                      //      8,224 B
  int* rowptr2 = (int*)(ws + 31875104);                      //      8,224 B
  int* cursor1 = (int*)(ws + 31883328);                      //      8,192 B
  int* cursor2 = (int*)(ws + 31891520);                      //      8,192 B
  __hip_bfloat16* kb = (__hip_bfloat16*)(ws + 31899712);     //  3,145,728 B (bf16 K)
  int* tslot2  = (int*)(ws + 35045440);                      //    524,288 B
  int* pos2    = (int*)(ws + 35569728);                      //    524,288 B
  int* eorig2  = (int*)(ws + 36094016);                      //    524,288 B
  // tgt-sort arrays overlap hsb (dead after qkv_gemm; single-stream ordered):
  int* src_s = (int*)ws;                                     //    524,288 B
  int* pos_s = (int*)(ws + 524288);                          //    524,288 B

  // 1) convert hs + weights to bf16; zero both hists
  //    threads = 393216 + 442368 + 1024 = 836608 = 3268 * 256
  convert_kernel<<<3268, 256, 0, stream>>>(hs, Wq, Wk, Wv, hsb, wb, hist1);

  // 2) QKV projection: 64x64 tiles; K emitted as bf16
  dim3 grid_gemm(32, 12, 3);
  qkv_gemm<<<grid_gemm, 256, 0, stream>>>(hsb, wb, bq, bk, bv, qkv, kb);

  const float* Qp = qkv;
  const float* Vp = qkv + (size_t)2 * NNODES * H;

  // 3-5) dual counting sort: tgt-CSR (scores) + src-CSR (output)
  hist_kernel<<<NEDGES / 256, 256, 0, stream>>>(etgt, esrc, hist1, hist2);
  scan_kernel<<<1, 256, 0, stream>>>(hist1, rowptr1, cursor1,
                                     hist2, rowptr2, cursor2);
  scatter_kernel<<<NEDGES / 256, 256, 0, stream>>>(esrc, etgt, epos,
                                                   cursor1, cursor2,
                                                   src_s, pos_s,
                                                   tslot2, pos2, eorig2);

  // 6) pass1: scores + on-chip denom + in-place normalize -> attn
  edge_scores_kernel<<<NNODES, 256, 0, stream>>>(Qp, kb, relk, rowptr1,
                                                 src_s, pos_s, attn);

  // 7) pass2: per-src V staging (V read ONCE), nt-stream output
  edge_out_kernel<<<NNODES, 256, 0, stream>>>(Vp, relv, rowptr2, tslot2, pos2,
                                              eorig2, attn, out);
}

// Round 8
// 532.535 us; speedup vs baseline: 1.0397x; 1.0397x over previous
//
#include <hip/hip_runtime.h>
#include <hip/hip_bf16.h>

#define H 768
#define NH 12
#define DH 64
#define NNODES 2048
#define NEDGES 131072

typedef __bf16 bf16x8 __attribute__((ext_vector_type(8)));
typedef float floatx4 __attribute__((ext_vector_type(4)));

// direct global->LDS DMA, 16B per lane (dest must be wave-uniform base + lane*16)
#define GLOAD_LDS16(gptr, ldsptr)                                                        \
  __builtin_amdgcn_global_load_lds((const __attribute__((address_space(1))) void*)(gptr), \
                                   (__attribute__((address_space(3))) void*)(ldsptr),     \
                                   16, 0, 0)

__device__ __forceinline__ unsigned short f2bf(float x) {
  union { __hip_bfloat16 h; unsigned short u; } cv;
  cv.h = __float2bfloat16(x);
  return cv.u;
}

// exact bf16 -> fp32 (bit shift)
__device__ __forceinline__ float bfu2f(unsigned short u) {
  union { float f; unsigned int i; } c;
  c.i = ((unsigned int)u) << 16;
  return c.f;
}

// ---------------- fp32 -> bf16 conversion (vectorized x4) + hist zero -------
__global__ __launch_bounds__(256)
void convert_kernel(const float* __restrict__ hs,
                    const float* __restrict__ Wq,
                    const float* __restrict__ Wk,
                    const float* __restrict__ Wv,
                    __hip_bfloat16* __restrict__ hsb,
                    __hip_bfloat16* __restrict__ wb,
                    int* __restrict__ hist) {
  int i = blockIdx.x * 256 + threadIdx.x;
  const int n_hs4 = NNODES * H / 4;   // 393216
  const int n_w4  = H * H / 4;        // 147456
  if (i < n_hs4) {
    float4 v = ((const float4*)hs)[i];
    ((ushort4*)hsb)[i] = make_ushort4(f2bf(v.x), f2bf(v.y), f2bf(v.z), f2bf(v.w));
    return;
  }
  int j = i - n_hs4;
  if (j < 3 * n_w4) {
    const float* src = (j < n_w4) ? Wq : (j < 2 * n_w4 ? Wk : Wv);
    float4 v = ((const float4*)src)[j % n_w4];
    ((ushort4*)wb)[j] = make_ushort4(f2bf(v.x), f2bf(v.y), f2bf(v.z), f2bf(v.w));
    return;
  }
  int z = j - 3 * n_w4;
  if (z < NNODES / 4) {               // 512 int4 = 2048 ints
    ((int4*)hist)[z] = make_int4(0, 0, 0, 0);
  }
}

// ---------------- QKV projection GEMM: C = A * W^T + bias -------------------
// 64x64 tiles, grid (32,12,3) = 1152 blocks; K (mat==1) emitted as bf16.
__global__ __launch_bounds__(256)
void qkv_gemm(const __hip_bfloat16* __restrict__ A,
              const __hip_bfloat16* __restrict__ Wb,
              const float* __restrict__ b0,
              const float* __restrict__ b1,
              const float* __restrict__ b2,
              float* __restrict__ out,
              __hip_bfloat16* __restrict__ kb) {
  __shared__ __hip_bfloat16 As[64][32];
  __shared__ __hip_bfloat16 Bs[64][32];

  const int t    = threadIdx.x;
  const int wave = t >> 6;
  const int lane = t & 63;
  const int bm   = blockIdx.x * 64;
  const int bn   = blockIdx.y * 64;
  const int mat  = blockIdx.z;

  const __hip_bfloat16* B = Wb + (size_t)mat * H * H;
  const float* bias = (mat == 0) ? b0 : ((mat == 1) ? b1 : b2);

  const int wm = (wave & 1) * 32;
  const int wn = (wave >> 1) * 32;
  const int lr = lane & 15;
  const int lq = lane >> 4;

  floatx4 acc[2][2] = {};

  const int ar = t >> 2;
  const int ac = (t & 3) * 8;
  __hip_bfloat16* AsF = &As[0][0];
  __hip_bfloat16* BsF = &Bs[0][0];

  for (int kt = 0; kt < H; kt += 32) {
    GLOAD_LDS16(A + (size_t)(bm + ar) * H + kt + ac, AsF + t * 8);
    GLOAD_LDS16(B + (size_t)(bn + ar) * H + kt + ac, BsF + t * 8);
    __syncthreads();

    bf16x8 af[2], bfr[2];
#pragma unroll
    for (int i = 0; i < 2; i++)
      af[i] = *(const bf16x8*)&As[wm + i * 16 + lr][lq * 8];
#pragma unroll
    for (int i = 0; i < 2; i++)
      bfr[i] = *(const bf16x8*)&Bs[wn + i * 16 + lr][lq * 8];
#pragma unroll
    for (int mi = 0; mi < 2; mi++)
#pragma unroll
      for (int ni = 0; ni < 2; ni++)
        acc[mi][ni] = __builtin_amdgcn_mfma_f32_16x16x32_bf16(
            af[mi], bfr[ni], acc[mi][ni], 0, 0, 0);
    __syncthreads();
  }

  // epilogue: C/D layout col = lane&15, row = (lane>>4)*4 + reg  [m89-verified]
  if (mat == 1) {
#pragma unroll
    for (int ni = 0; ni < 2; ni++) {
      int col = bn + wn + ni * 16 + lr;
      float bv = bias[col];
#pragma unroll
      for (int mi = 0; mi < 2; mi++) {
#pragma unroll
        for (int r = 0; r < 4; r++) {
          int row = bm + wm + mi * 16 + lq * 4 + r;
          kb[(size_t)row * H + col] = __float2bfloat16(acc[mi][ni][r] + bv);
        }
      }
    }
  } else {
    float* C = out + (size_t)mat * NNODES * H;
#pragma unroll
    for (int ni = 0; ni < 2; ni++) {
      int col = bn + wn + ni * 16 + lr;
      float bv = bias[col];
#pragma unroll
      for (int mi = 0; mi < 2; mi++) {
#pragma unroll
        for (int r = 0; r < 4; r++) {
          int row = bm + wm + mi * 16 + lq * 4 + r;
          C[(size_t)row * H + col] = acc[mi][ni][r] + bv;
        }
      }
    }
  }
}

// ---------------- counting sort by tgt: histogram ---------------------------
__global__ __launch_bounds__(256)
void hist_kernel(const int* __restrict__ etgt, int* __restrict__ hist) {
  int e = blockIdx.x * 256 + threadIdx.x;
  atomicAdd(&hist[etgt[e]], 1);
}

// ---------------- counting sort: exclusive prefix sum (1 block) -------------
__global__ __launch_bounds__(256)
void scan_kernel(const int* __restrict__ hist, int* __restrict__ rowptr,
                 int* __restrict__ cursor) {
  __shared__ int part[256];
  int t = threadIdx.x;
  int loc[8];
  int s = 0;
#pragma unroll
  for (int k = 0; k < 8; k++) { loc[k] = s; s += hist[t * 8 + k]; }
  part[t] = s;
  __syncthreads();
  for (int off = 1; off < 256; off <<= 1) {
    int v = (t >= off) ? part[t - off] : 0;
    __syncthreads();
    if (t >= off) part[t] += v;
    __syncthreads();
  }
  int pre = part[t] - s;
#pragma unroll
  for (int k = 0; k < 8; k++) {
    rowptr[t * 8 + k] = pre + loc[k];
    cursor[t * 8 + k] = pre + loc[k];
  }
  if (t == 255) rowptr[NNODES] = part[255];
}

// ---------------- counting sort: scatter (stores orig edge id) --------------
__global__ __launch_bounds__(256)
void scatter_kernel(const int* __restrict__ esrc, const int* __restrict__ etgt,
                    const int* __restrict__ epos,
                    int* __restrict__ cursor,
                    int* __restrict__ src_s, int* __restrict__ pos_s,
                    int* __restrict__ eorig) {
  int e = blockIdx.x * 256 + threadIdx.x;
  int tgt = etgt[e];
  int slot = atomicAdd(&cursor[tgt], 1);
  src_s[slot] = esrc[e];
  pos_s[slot] = epos[e];
  eorig[slot] = e;
}

// ---------------- fused edge phase: one block per target node ---------------
// 2-edge-unrolled per wave: both edges' gathers issue before either compute
// consumes (2x memory-level parallelism on the dependent src->row chain).
__global__ __launch_bounds__(256)
void edge_fused_kernel(const float* __restrict__ Q,
                       const __hip_bfloat16* __restrict__ Kb,
                       const float* __restrict__ V,
                       const float* __restrict__ relk,
                       const float* __restrict__ relv,
                       const int* __restrict__ rowptr,
                       const int* __restrict__ src_s,
                       const int* __restrict__ pos_s,
                       const int* __restrict__ eorig,
                       float* __restrict__ scores_s,
                       float* __restrict__ out) {
  const int t    = blockIdx.x;
  const int tid  = threadIdx.x;
  const int wave = tid >> 6;
  const int lane = tid & 63;
  const int g    = lane >> 4;
  const int off  = (lane & 15) * 4;

  __shared__ float Qs[H];            // 3 KB
  __shared__ float Rs[16 * DH];      // 4 KB (relk in pass1, relv in pass2)
  __shared__ float dpart[4][NH];
  __shared__ float dinv[NH];

  if (tid < 192)
    *(float4*)&Qs[tid * 4] = *(const float4*)(Q + (size_t)t * H + tid * 4);
  *(float4*)&Rs[tid * 4] = *(const float4*)(relk + tid * 4);
  __syncthreads();

  const int beg = rowptr[t], end = rowptr[t + 1];
  float dacc0 = 0.f, dacc1 = 0.f, dacc2 = 0.f;

  // ---- pass 1: exp-scores + register denom (2-edge unroll) ----
  for (int i = beg + wave; i < end; i += 8) {
    const bool has2 = (i + 4) < end;
    const int iB = has2 ? i + 4 : i;
    const int srcA = src_s[i],  posA = pos_s[i];
    const int srcB = src_s[iB], posB = pos_s[iB];
    const unsigned short* KpA = (const unsigned short*)(Kb + (size_t)srcA * H);
    const unsigned short* KpB = (const unsigned short*)(Kb + (size_t)srcB * H);
    ushort4 kuA[3], kuB[3];
#pragma unroll
    for (int c = 0; c < 3; c++) kuA[c] = *(const ushort4*)(KpA + c * 256 + lane * 4);
#pragma unroll
    for (int c = 0; c < 3; c++) kuB[c] = *(const ushort4*)(KpB + c * 256 + lane * 4);
    const float4 rA = *(const float4*)&Rs[posA * DH + off];
    const float4 rB = *(const float4*)&Rs[posB * DH + off];
    float sA[3], sB[3];
#pragma unroll
    for (int c = 0; c < 3; c++) {
      float4 q4 = *(const float4*)&Qs[c * 256 + lane * 4];
      sA[c] = q4.x * (bfu2f(kuA[c].x) + rA.x) + q4.y * (bfu2f(kuA[c].y) + rA.y) +
              q4.z * (bfu2f(kuA[c].z) + rA.z) + q4.w * (bfu2f(kuA[c].w) + rA.w);
      sB[c] = q4.x * (bfu2f(kuB[c].x) + rB.x) + q4.y * (bfu2f(kuB[c].y) + rB.y) +
              q4.z * (bfu2f(kuB[c].z) + rB.z) + q4.w * (bfu2f(kuB[c].w) + rB.w);
    }
#pragma unroll
    for (int m = 1; m < 16; m <<= 1) {
      sA[0] += __shfl_xor(sA[0], m);
      sA[1] += __shfl_xor(sA[1], m);
      sA[2] += __shfl_xor(sA[2], m);
      sB[0] += __shfl_xor(sB[0], m);
      sB[1] += __shfl_xor(sB[1], m);
      sB[2] += __shfl_xor(sB[2], m);
    }
    if ((lane & 15) == 0) {
      float a0 = __expf(sA[0] * 0.125f);
      float a1 = __expf(sA[1] * 0.125f);
      float a2 = __expf(sA[2] * 0.125f);
      scores_s[(size_t)i * NH + g]     = a0;
      scores_s[(size_t)i * NH + 4 + g] = a1;
      scores_s[(size_t)i * NH + 8 + g] = a2;
      dacc0 += a0; dacc1 += a1; dacc2 += a2;
      if (has2) {
        float b0 = __expf(sB[0] * 0.125f);
        float b1 = __expf(sB[1] * 0.125f);
        float b2 = __expf(sB[2] * 0.125f);
        scores_s[(size_t)iB * NH + g]     = b0;
        scores_s[(size_t)iB * NH + 4 + g] = b1;
        scores_s[(size_t)iB * NH + 8 + g] = b2;
        dacc0 += b0; dacc1 += b1; dacc2 += b2;
      }
    }
  }

  if ((lane & 15) == 0) {
    dpart[wave][g]     = dacc0;
    dpart[wave][4 + g] = dacc1;
    dpart[wave][8 + g] = dacc2;
  }
  __syncthreads();   // drains pass1 global stores (vmcnt(0) before s_barrier)

  // swap Rs to relv; compute 1/denom
  *(float4*)&Rs[tid * 4] = *(const float4*)(relv + tid * 4);
  if (tid < NH) {
    float den = dpart[0][tid] + dpart[1][tid] + dpart[2][tid] + dpart[3][tid];
    dinv[tid] = 1.0f / den;    // IEEE div: <=1 ulp vs per-edge div
  }
  __syncthreads();

  // ---- pass 2: normalize, V gather, nt-write (2-edge unroll) ----
  for (int i = beg + wave; i < end; i += 8) {
    const bool has2 = (i + 4) < end;
    const int iB = has2 ? i + 4 : i;
    const int srcA = src_s[i],  posA = pos_s[i],  eA = eorig[i];
    const int srcB = src_s[iB], posB = pos_s[iB], eB = eorig[iB];
    // issue all gathers up front: 6 V-chunk loads + 6 score loads
    float4 vA[3], vB[3];
    float scA[3], scB[3];
#pragma unroll
    for (int c = 0; c < 3; c++)
      vA[c] = *(const float4*)(V + (size_t)srcA * H + c * 256 + lane * 4);
#pragma unroll
    for (int c = 0; c < 3; c++)
      vB[c] = *(const float4*)(V + (size_t)srcB * H + c * 256 + lane * 4);
#pragma unroll
    for (int c = 0; c < 3; c++) scA[c] = scores_s[(size_t)i * NH + c * 4 + g];
#pragma unroll
    for (int c = 0; c < 3; c++) scB[c] = scores_s[(size_t)iB * NH + c * 4 + g];
    const float4 rA = *(const float4*)&Rs[posA * DH + off];
    const float4 rB = *(const float4*)&Rs[posB * DH + off];
#pragma unroll
    for (int c = 0; c < 3; c++) {
      float a = scA[c] * dinv[c * 4 + g];
      floatx4 o;
      o.x = (vA[c].x + rA.x) * a;
      o.y = (vA[c].y + rA.y) * a;
      o.z = (vA[c].z + rA.z) * a;
      o.w = (vA[c].w + rA.w) * a;
      __builtin_nontemporal_store(
          o, (floatx4*)(out + (size_t)eA * H + c * 256 + lane * 4));
    }
    if (has2) {
#pragma unroll
      for (int c = 0; c < 3; c++) {
        float a = scB[c] * dinv[c * 4 + g];
        floatx4 o;
        o.x = (vB[c].x + rB.x) * a;
        o.y = (vB[c].y + rB.y) * a;
        o.z = (vB[c].z + rB.z) * a;
        o.w = (vB[c].w + rB.w) * a;
        __builtin_nontemporal_store(
            o, (floatx4*)(out + (size_t)eB * H + c * 256 + lane * 4));
      }
    }
  }
}

extern "C" void kernel_launch(void* const* d_in, const int* in_sizes, int n_in,
                              void* d_out, int out_size, void* d_ws, size_t ws_size,
                              hipStream_t stream) {
  const float* hs   = (const float*)d_in[0];
  const float* Wq   = (const float*)d_in[1];
  const float* bq   = (const float*)d_in[2];
  const float* Wk   = (const float*)d_in[3];
  const float* bk   = (const float*)d_in[4];
  const float* Wv   = (const float*)d_in[5];
  const float* bv   = (const float*)d_in[6];
  const float* relk = (const float*)d_in[7];
  const float* relv = (const float*)d_in[8];
  const int* esrc   = (const int*)d_in[9];
  const int* etgt   = (const int*)d_in[10];
  const int* epos   = (const int*)d_in[12];
  float* out = (float*)d_out;

  char* ws = (char*)d_ws;
  __hip_bfloat16* hsb = (__hip_bfloat16*)ws;                 //  3,145,728 B
  __hip_bfloat16* wb  = (__hip_bfloat16*)(ws + 3145728);     //  3,538,944 B
  float* qkv      = (float*)(ws + 6684672);                  // 18,874,368 B (K slot unused)
  float* scores_s = (float*)(ws + 25559040);                 //  6,291,456 B
  int* hist       = (int*)(ws + 31948800);                   //      8,192 B
  int* rowptr     = (int*)(ws + 31956992);                   //      8,208 B
  int* cursor     = (int*)(ws + 31965200);                   //      8,192 B
  __hip_bfloat16* kb = (__hip_bfloat16*)(ws + 31973392);     //  3,145,728 B (bf16 K)
  // sort arrays overlap hsb (hsb dead after qkv_gemm; stream-ordered):
  int* src_s = (int*)ws;                                     //    524,288 B
  int* pos_s = (int*)(ws + 524288);                          //    524,288 B
  int* eorig = (int*)(ws + 1048576);                         //    524,288 B

  // 1) convert hs + weights to bf16; zero hist
  convert_kernel<<<3266, 256, 0, stream>>>(hs, Wq, Wk, Wv, hsb, wb, hist);

  // 2) QKV projection: 64x64 tiles; K emitted as bf16
  dim3 grid_gemm(32, 12, 3);
  qkv_gemm<<<grid_gemm, 256, 0, stream>>>(hsb, wb, bq, bk, bv, qkv, kb);

  const float* Qp = qkv;
  const float* Vp = qkv + (size_t)2 * NNODES * H;

  // 3-5) counting sort of edges by tgt -> CSR (+ orig edge id per slot)
  hist_kernel<<<NEDGES / 256, 256, 0, stream>>>(etgt, hist);
  scan_kernel<<<1, 256, 0, stream>>>(hist, rowptr, cursor);
  scatter_kernel<<<NEDGES / 256, 256, 0, stream>>>(esrc, etgt, epos, cursor,
                                                   src_s, pos_s, eorig);

  // 6) fused scores + normalize + weighted output (2-edge unrolled waves)
  edge_fused_kernel<<<NNODES, 256, 0, stream>>>(Qp, kb, Vp, relk, relv, rowptr,
                                                src_s, pos_s, eorig,
                                                scores_s, out);
}

// Round 9
// 523.687 us; speedup vs baseline: 1.0572x; 1.0169x over previous
//
#include <hip/hip_runtime.h>
#include <hip/hip_bf16.h>

#define H 768
#define NH 12
#define DH 64
#define NNODES 2048
#define NEDGES 131072

typedef __bf16 bf16x8 __attribute__((ext_vector_type(8)));
typedef float floatx4 __attribute__((ext_vector_type(4)));

// direct global->LDS DMA, 16B per lane (dest must be wave-uniform base + lane*16)
#define GLOAD_LDS16(gptr, ldsptr)                                                        \
  __builtin_amdgcn_global_load_lds((const __attribute__((address_space(1))) void*)(gptr), \
                                   (__attribute__((address_space(3))) void*)(ldsptr),     \
                                   16, 0, 0)

__device__ __forceinline__ unsigned short f2bf(float x) {
  union { __hip_bfloat16 h; unsigned short u; } cv;
  cv.h = __float2bfloat16(x);
  return cv.u;
}

// exact bf16 -> fp32 (bit shift)
__device__ __forceinline__ float bfu2f(unsigned short u) {
  union { float f; unsigned int i; } c;
  c.i = ((unsigned int)u) << 16;
  return c.f;
}

// ---------------- fp32 -> bf16 conversion (vectorized x4) + hist zero -------
// hist zeroing completes before qkv_gemm (stream-ordered), which does the
// histogram atomics in its prologue.
__global__ __launch_bounds__(256)
void convert_kernel(const float* __restrict__ hs,
                    const float* __restrict__ Wq,
                    const float* __restrict__ Wk,
                    const float* __restrict__ Wv,
                    __hip_bfloat16* __restrict__ hsb,
                    __hip_bfloat16* __restrict__ wb,
                    int* __restrict__ hist) {
  int i = blockIdx.x * 256 + threadIdx.x;
  const int n_hs4 = NNODES * H / 4;   // 393216
  const int n_w4  = H * H / 4;        // 147456
  if (i < n_hs4) {
    float4 v = ((const float4*)hs)[i];
    ((ushort4*)hsb)[i] = make_ushort4(f2bf(v.x), f2bf(v.y), f2bf(v.z), f2bf(v.w));
    return;
  }
  int j = i - n_hs4;
  if (j < 3 * n_w4) {
    const float* src = (j < n_w4) ? Wq : (j < 2 * n_w4 ? Wk : Wv);
    float4 v = ((const float4*)src)[j % n_w4];
    ((ushort4*)wb)[j] = make_ushort4(f2bf(v.x), f2bf(v.y), f2bf(v.z), f2bf(v.w));
    return;
  }
  int z = j - 3 * n_w4;
  if (z < NNODES / 4) {               // 512 int4 = 2048 ints
    ((int4*)hist)[z] = make_int4(0, 0, 0, 0);
  }
}

// ---------------- QKV projection GEMM + fused edge histogram ---------------
// 64x64 tiles, grid (32,12,3) = 1152 blocks; K (mat==1) emitted as bf16.
// Prologue: each thread histograms <=1 edge (294912 threads >= 131072 edges);
// the atomics hide under the GEMM's staging latency, saving a launch.
__global__ __launch_bounds__(256)
void qkv_gemm(const __hip_bfloat16* __restrict__ A,
              const __hip_bfloat16* __restrict__ Wb,
              const float* __restrict__ b0,
              const float* __restrict__ b1,
              const float* __restrict__ b2,
              float* __restrict__ out,
              __hip_bfloat16* __restrict__ kb,
              const int* __restrict__ etgt,
              int* __restrict__ hist) {
  __shared__ __hip_bfloat16 As[64][32];
  __shared__ __hip_bfloat16 Bs[64][32];

  const int t    = threadIdx.x;
  const int wave = t >> 6;
  const int lane = t & 63;
  const int bm   = blockIdx.x * 64;
  const int bn   = blockIdx.y * 64;
  const int mat  = blockIdx.z;

  // fused histogram (hist was zeroed by convert_kernel, stream-ordered)
  {
    int flatb = blockIdx.x + 32 * (blockIdx.y + 12 * blockIdx.z);
    int e = flatb * 256 + t;
    if (e < NEDGES) atomicAdd(&hist[etgt[e]], 1);
  }

  const __hip_bfloat16* B = Wb + (size_t)mat * H * H;
  const float* bias = (mat == 0) ? b0 : ((mat == 1) ? b1 : b2);

  const int wm = (wave & 1) * 32;
  const int wn = (wave >> 1) * 32;
  const int lr = lane & 15;
  const int lq = lane >> 4;

  floatx4 acc[2][2] = {};

  const int ar = t >> 2;
  const int ac = (t & 3) * 8;
  __hip_bfloat16* AsF = &As[0][0];
  __hip_bfloat16* BsF = &Bs[0][0];

  for (int kt = 0; kt < H; kt += 32) {
    GLOAD_LDS16(A + (size_t)(bm + ar) * H + kt + ac, AsF + t * 8);
    GLOAD_LDS16(B + (size_t)(bn + ar) * H + kt + ac, BsF + t * 8);
    __syncthreads();

    bf16x8 af[2], bfr[2];
#pragma unroll
    for (int i = 0; i < 2; i++)
      af[i] = *(const bf16x8*)&As[wm + i * 16 + lr][lq * 8];
#pragma unroll
    for (int i = 0; i < 2; i++)
      bfr[i] = *(const bf16x8*)&Bs[wn + i * 16 + lr][lq * 8];
#pragma unroll
    for (int mi = 0; mi < 2; mi++)
#pragma unroll
      for (int ni = 0; ni < 2; ni++)
        acc[mi][ni] = __builtin_amdgcn_mfma_f32_16x16x32_bf16(
            af[mi], bfr[ni], acc[mi][ni], 0, 0, 0);
    __syncthreads();
  }

  // epilogue: C/D layout col = lane&15, row = (lane>>4)*4 + reg  [m89-verified]
  if (mat == 1) {
#pragma unroll
    for (int ni = 0; ni < 2; ni++) {
      int col = bn + wn + ni * 16 + lr;
      float bv = bias[col];
#pragma unroll
      for (int mi = 0; mi < 2; mi++) {
#pragma unroll
        for (int r = 0; r < 4; r++) {
          int row = bm + wm + mi * 16 + lq * 4 + r;
          kb[(size_t)row * H + col] = __float2bfloat16(acc[mi][ni][r] + bv);
        }
      }
    }
  } else {
    float* C = out + (size_t)mat * NNODES * H;
#pragma unroll
    for (int ni = 0; ni < 2; ni++) {
      int col = bn + wn + ni * 16 + lr;
      float bv = bias[col];
#pragma unroll
      for (int mi = 0; mi < 2; mi++) {
#pragma unroll
        for (int r = 0; r < 4; r++) {
          int row = bm + wm + mi * 16 + lq * 4 + r;
          C[(size_t)row * H + col] = acc[mi][ni][r] + bv;
        }
      }
    }
  }
}

// ---------------- counting sort: exclusive prefix sum (1 block) -------------
__global__ __launch_bounds__(256)
void scan_kernel(const int* __restrict__ hist, int* __restrict__ rowptr,
                 int* __restrict__ cursor) {
  __shared__ int part[256];
  int t = threadIdx.x;
  int loc[8];
  int s = 0;
#pragma unroll
  for (int k = 0; k < 8; k++) { loc[k] = s; s += hist[t * 8 + k]; }
  part[t] = s;
  __syncthreads();
  for (int off = 1; off < 256; off <<= 1) {
    int v = (t >= off) ? part[t - off] : 0;
    __syncthreads();
    if (t >= off) part[t] += v;
    __syncthreads();
  }
  int pre = part[t] - s;
#pragma unroll
  for (int k = 0; k < 8; k++) {
    rowptr[t * 8 + k] = pre + loc[k];
    cursor[t * 8 + k] = pre + loc[k];
  }
  if (t == 255) rowptr[NNODES] = part[255];
}

// ---------------- counting sort: scatter (stores orig edge id) --------------
__global__ __launch_bounds__(256)
void scatter_kernel(const int* __restrict__ esrc, const int* __restrict__ etgt,
                    const int* __restrict__ epos,
                    int* __restrict__ cursor,
                    int* __restrict__ src_s, int* __restrict__ pos_s,
                    int* __restrict__ eorig) {
  int e = blockIdx.x * 256 + threadIdx.x;
  int tgt = etgt[e];
  int slot = atomicAdd(&cursor[tgt], 1);
  src_s[slot] = esrc[e];
  pos_s[slot] = epos[e];
  eorig[slot] = e;
}

// ---------------- fused edge phase: one block per target node ---------------
// pass1: scores (bf16 K gather) -> scores_s + in-LDS denom (zero atomics)
// pass2: attn = sc * (1/denom), V gather, nt-write out[eorig] (3KB contiguous)
// [best-measured variant, R6: 526 us; 2-edge unroll (R8) regressed -6 us]
__global__ __launch_bounds__(256)
void edge_fused_kernel(const float* __restrict__ Q,
                       const __hip_bfloat16* __restrict__ Kb,
                       const float* __restrict__ V,
                       const float* __restrict__ relk,
                       const float* __restrict__ relv,
                       const int* __restrict__ rowptr,
                       const int* __restrict__ src_s,
                       const int* __restrict__ pos_s,
                       const int* __restrict__ eorig,
                       float* __restrict__ scores_s,
                       float* __restrict__ out) {
  const int t    = blockIdx.x;
  const int tid  = threadIdx.x;
  const int wave = tid >> 6;
  const int lane = tid & 63;
  const int g    = lane >> 4;
  const int off  = (lane & 15) * 4;

  __shared__ float Qs[H];            // 3 KB
  __shared__ float Rs[16 * DH];      // 4 KB (relk in pass1, relv in pass2)
  __shared__ float dpart[4][NH];
  __shared__ float dinv[NH];

  if (tid < 192)
    *(float4*)&Qs[tid * 4] = *(const float4*)(Q + (size_t)t * H + tid * 4);
  *(float4*)&Rs[tid * 4] = *(const float4*)(relk + tid * 4);
  __syncthreads();

  const int beg = rowptr[t], end = rowptr[t + 1];
  float dacc0 = 0.f, dacc1 = 0.f, dacc2 = 0.f;

  // ---- pass 1: exp-scores + register denom ----
  for (int i = beg + wave; i < end; i += 4) {
    const int src = src_s[i];
    const int pos = pos_s[i];
    const unsigned short* Kp = (const unsigned short*)(Kb + (size_t)src * H);
    const float4 r4 = *(const float4*)&Rs[pos * DH + off];
    float s[3];
#pragma unroll
    for (int c = 0; c < 3; c++) {
      ushort4 ku = *(const ushort4*)(Kp + c * 256 + lane * 4);
      float4 q4 = *(const float4*)&Qs[c * 256 + lane * 4];
      s[c] = q4.x * (bfu2f(ku.x) + r4.x) + q4.y * (bfu2f(ku.y) + r4.y) +
             q4.z * (bfu2f(ku.z) + r4.z) + q4.w * (bfu2f(ku.w) + r4.w);
    }
#pragma unroll
    for (int m = 1; m < 16; m <<= 1) {
      s[0] += __shfl_xor(s[0], m);
      s[1] += __shfl_xor(s[1], m);
      s[2] += __shfl_xor(s[2], m);
    }
    if ((lane & 15) == 0) {
      float sc0 = __expf(s[0] * 0.125f);
      float sc1 = __expf(s[1] * 0.125f);
      float sc2 = __expf(s[2] * 0.125f);
      scores_s[(size_t)i * NH + g]     = sc0;
      scores_s[(size_t)i * NH + 4 + g] = sc1;
      scores_s[(size_t)i * NH + 8 + g] = sc2;
      dacc0 += sc0; dacc1 += sc1; dacc2 += sc2;
    }
  }

  if ((lane & 15) == 0) {
    dpart[wave][g]     = dacc0;
    dpart[wave][4 + g] = dacc1;
    dpart[wave][8 + g] = dacc2;
  }
  __syncthreads();   // drains pass1 global stores (vmcnt(0) before s_barrier)

  // swap Rs to relv; compute 1/denom
  *(float4*)&Rs[tid * 4] = *(const float4*)(relv + tid * 4);
  if (tid < NH) {
    float den = dpart[0][tid] + dpart[1][tid] + dpart[2][tid] + dpart[3][tid];
    dinv[tid] = 1.0f / den;    // IEEE div: <=1 ulp vs per-edge div
  }
  __syncthreads();

  // ---- pass 2: normalize, V gather, nt-write ----
  for (int i = beg + wave; i < end; i += 4) {
    const int src = src_s[i];
    const int pos = pos_s[i];
    const int e   = eorig[i];
    const float4 r4 = *(const float4*)&Rs[pos * DH + off];
#pragma unroll
    for (int c = 0; c < 3; c++) {
      int h = c * 4 + g;
      float a = scores_s[(size_t)i * NH + h] * dinv[h];   // L2-hot, block-local
      float4 v4 = *(const float4*)(V + (size_t)src * H + c * 256 + lane * 4);
      floatx4 o;
      o.x = (v4.x + r4.x) * a;
      o.y = (v4.y + r4.y) * a;
      o.z = (v4.z + r4.z) * a;
      o.w = (v4.w + r4.w) * a;
      __builtin_nontemporal_store(
          o, (floatx4*)(out + (size_t)e * H + c * 256 + lane * 4));
    }
  }
}

extern "C" void kernel_launch(void* const* d_in, const int* in_sizes, int n_in,
                              void* d_out, int out_size, void* d_ws, size_t ws_size,
                              hipStream_t stream) {
  const float* hs   = (const float*)d_in[0];
  const float* Wq   = (const float*)d_in[1];
  const float* bq   = (const float*)d_in[2];
  const float* Wk   = (const float*)d_in[3];
  const float* bk   = (const float*)d_in[4];
  const float* Wv   = (const float*)d_in[5];
  const float* bv   = (const float*)d_in[6];
  const float* relk = (const float*)d_in[7];
  const float* relv = (const float*)d_in[8];
  const int* esrc   = (const int*)d_in[9];
  const int* etgt   = (const int*)d_in[10];
  const int* epos   = (const int*)d_in[12];
  float* out = (float*)d_out;

  char* ws = (char*)d_ws;
  __hip_bfloat16* hsb = (__hip_bfloat16*)ws;                 //  3,145,728 B
  __hip_bfloat16* wb  = (__hip_bfloat16*)(ws + 3145728);     //  3,538,944 B
  float* qkv      = (float*)(ws + 6684672);                  // 18,874,368 B (K slot unused)
  float* scores_s = (float*)(ws + 25559040);                 //  6,291,456 B
  int* hist       = (int*)(ws + 31948800);                   //      8,192 B
  int* rowptr     = (int*)(ws + 31956992);                   //      8,208 B
  int* cursor     = (int*)(ws + 31965200);                   //      8,192 B
  __hip_bfloat16* kb = (__hip_bfloat16*)(ws + 31973392);     //  3,145,728 B (bf16 K)
  // sort arrays overlap hsb (hsb dead after qkv_gemm; stream-ordered):
  int* src_s = (int*)ws;                                     //    524,288 B
  int* pos_s = (int*)(ws + 524288);                          //    524,288 B
  int* eorig = (int*)(ws + 1048576);                         //    524,288 B

  // 1) convert hs + weights to bf16; zero hist
  convert_kernel<<<3266, 256, 0, stream>>>(hs, Wq, Wk, Wv, hsb, wb, hist);

  // 2) QKV projection (K as bf16) + fused edge histogram
  dim3 grid_gemm(32, 12, 3);
  qkv_gemm<<<grid_gemm, 256, 0, stream>>>(hsb, wb, bq, bk, bv, qkv, kb,
                                          etgt, hist);

  const float* Qp = qkv;
  const float* Vp = qkv + (size_t)2 * NNODES * H;

  // 3-4) counting sort of edges by tgt -> CSR (+ orig edge id per slot)
  scan_kernel<<<1, 256, 0, stream>>>(hist, rowptr, cursor);
  scatter_kernel<<<NEDGES / 256, 256, 0, stream>>>(esrc, etgt, epos, cursor,
                                                   src_s, pos_s, eorig);

  // 5) fused scores + normalize + weighted output (denom stays on-chip)
  edge_fused_kernel<<<NNODES, 256, 0, stream>>>(Qp, kb, Vp, relk, relv, rowptr,
                                                src_s, pos_s, eorig,
                                                scores_s, out);
}